// Round 1
// baseline (907.629 us; speedup 1.0000x reference)
//
#include <hip/hip_runtime.h>
#include <math.h>

#define NTHREADS 256
#define G3   4096
#define DWN  15
#define DW2  225
#define DW3  3375
#define NCH  8
#define VOL  64
#define VOL3 (VOL*VOL*VOL)
#define REG  18
#define REG2 (REG*REG)
#define REG3 (REG*REG*REG)
// LDS pool for the displacement-domain filter: v[3375] | A[6859] | B[6859]
#define POOLSZ 17093
#define OFF_A  3375
#define OFF_B  10234

// ---------------------------------------------------------------------------
// Displacement-domain filter (per grid point, all in LDS):
//   out = avgp3(avgp3(-maxp3(-rpad3(v))))
// = separable min-3 (clamped, extended to 19/axis) then separable 5-tap
//   [1,2,3,2,1]/9 smoothing back down to 15/axis.
// pool layout: v = pool[0..3374] ([kz][ky][kx]); temps A, B. Writes gout[3375].
// ---------------------------------------------------------------------------
__device__ __forceinline__ void disp_filter(float* pool, int tid, float* gout)
{
    const float w0 = 1.0f/9.0f, w1 = 2.0f/9.0f, w2 = 3.0f/9.0f;
    float* v = pool;
    float* A = pool + OFF_A;
    float* B = pool + OFF_B;
    // min over x: [15][15][19] -> A
    for (int e = tid; e < 15*15*19; e += NTHREADS) {
        int x = e % 19; int zy = e / 19;
        int i0 = max(0, min(14, x-3));
        int i1 = max(0, min(14, x-2));
        int i2 = max(0, min(14, x-1));
        const float* row = v + zy*15;
        A[e] = fminf(fminf(row[i0], row[i1]), row[i2]);
    }
    __syncthreads();
    // min over y: [15][19][19] -> B
    for (int e = tid; e < 15*19*19; e += NTHREADS) {
        int x = e % 19; int y = (e/19) % 19; int z = e/361;
        int i0 = max(0, min(14, y-3));
        int i1 = max(0, min(14, y-2));
        int i2 = max(0, min(14, y-1));
        const float* base = A + z*285 + x;   // 15*19 = 285
        B[e] = fminf(fminf(base[i0*19], base[i1*19]), base[i2*19]);
    }
    __syncthreads();
    // min over z: [19][19][19] -> A
    for (int e = tid; e < 19*19*19; e += NTHREADS) {
        int xy = e % 361; int z = e/361;
        int i0 = max(0, min(14, z-3));
        int i1 = max(0, min(14, z-2));
        int i2 = max(0, min(14, z-1));
        const float* base = B + xy;
        A[e] = fminf(fminf(base[i0*361], base[i1*361]), base[i2*361]);
    }
    __syncthreads();
    // smooth x: [19][19][15] -> B
    for (int e = tid; e < 19*19*15; e += NTHREADS) {
        int i = e % 15; int zy = e/15;
        const float* row = A + zy*19 + i;
        B[e] = w0*(row[0]+row[4]) + w1*(row[1]+row[3]) + w2*row[2];
    }
    __syncthreads();
    // smooth y: [19][15][15] -> pool[0..4274]  (v and head of A are dead)
    for (int e = tid; e < 19*15*15; e += NTHREADS) {
        int i = e % 15; int j = (e/15)%15; int z = e/225;
        const float* base = B + (z*19 + j)*15 + i;
        pool[e] = w0*(base[0]+base[60]) + w1*(base[15]+base[45]) + w2*base[30];
    }
    __syncthreads();
    // smooth z: [15][15][15] -> global
    for (int e = tid; e < DW3; e += NTHREADS) {
        int ji = e % 225; int k = e/225;
        const float* base = pool + k*225 + ji;
        gout[e] = w0*(base[0]+base[900]) + w1*(base[225]+base[675]) + w2*base[450];
    }
}

// ---------------------------------------------------------------------------
// K1: per grid point — trilinear SSD correlation (LDS-staged 18^3 window,
// 2 channels/pass as float2) + fused displacement-domain filter.
// Writes deeds_cost (ws) and cost1 ([g][d], into d_out region).
// ---------------------------------------------------------------------------
__global__ __launch_bounds__(NTHREADS) void k1_sample(
    const float* __restrict__ feat00, const float* __restrict__ feat50,
    const float* __restrict__ grid_xyz, const float* __restrict__ alpha,
    float* __restrict__ deeds, float* __restrict__ cost1)
{
    __shared__ float pool[POOLSZ];
    __shared__ float tT[45];
    __shared__ int   tI0[45];
    __shared__ int   tI1[45];
    __shared__ float fixedv[NCH];
    __shared__ int   loS[3];
    __shared__ float gpos[3];

    const int tid = threadIdx.x;
    const int g = blockIdx.x;

    float* ssdL = pool + 11664;                 // [3375], after the 2*REG3 staging area
    for (int e = tid; e < DW3; e += NTHREADS) ssdL[e] = 0.0f;

    if (tid < 3) {
        float p = (grid_xyz[g*3 + tid] + 1.0f) * 31.5f;   // voxel coords, in [0,63]
        int lo = (int)floorf(p) - 8;                       // 18-wide window start
        lo = lo < 0 ? 0 : (lo > 46 ? 46 : lo);
        loS[tid] = lo;
        gpos[tid] = p;
    }
    __syncthreads();
    // per-axis interpolation tables for the 15 displacement taps (border clamp)
    if (tid < 45) {
        int ax = tid / 15, k = tid - ax*15;
        float p = gpos[ax] + (1.125f*(float)k - 7.875f);
        p = fminf(fmaxf(p, 0.0f), 63.0f);
        float f = floorf(p);
        int i0 = (int)f;
        int i1 = i0 + 1 > 63 ? 63 : i0 + 1;
        tT[tid] = p - f;
        tI0[tid] = i0 - loS[ax];
        tI1[tid] = i1 - loS[ax];
    }
    // fixed sample from feat00 (coords in [0,63]; clamped corner == zeros-pad here)
    if (tid < NCH) {
        float px = gpos[0], py = gpos[1], pz = gpos[2];
        int x0 = (int)floorf(px), y0 = (int)floorf(py), z0 = (int)floorf(pz);
        float tx = px-(float)x0, ty = py-(float)y0, tz = pz-(float)z0;
        int x1 = x0+1>63?63:x0+1, y1 = y0+1>63?63:y0+1, z1 = z0+1>63?63:z0+1;
        const float* F = feat00 + (size_t)tid * VOL3;
        float v000=F[(z0*64+y0)*64+x0], v001=F[(z0*64+y0)*64+x1];
        float v010=F[(z0*64+y1)*64+x0], v011=F[(z0*64+y1)*64+x1];
        float v100=F[(z1*64+y0)*64+x0], v101=F[(z1*64+y0)*64+x1];
        float v110=F[(z1*64+y1)*64+x0], v111=F[(z1*64+y1)*64+x1];
        float wx0=1.0f-tx, wy0=1.0f-ty, wz0=1.0f-tz;
        fixedv[tid] =
            wz0*(wy0*(wx0*v000 + tx*v001) + ty*(wx0*v010 + tx*v011)) +
            tz *(wy0*(wx0*v100 + tx*v101) + ty*(wx0*v110 + tx*v111));
    }

    const float a0 = alpha[0], a1 = alpha[1];

    for (int cp = 0; cp < 4; ++cp) {
        __syncthreads();                          // prev reads done / tables ready
        const int lx = loS[0], ly = loS[1], lz = loS[2];
        const float* F0 = feat50 + (size_t)(2*cp) * VOL3;
        // stage 18^3 window for channels 2cp, 2cp+1, interleaved as float2
        for (int e = tid; e < 2*REG3; e += NTHREADS) {
            int ch = (e < REG3) ? 0 : 1;
            int r = e - ch*REG3;
            int rz = r / REG2;
            int rem = r - rz*REG2;
            int ry = rem / REG;
            int rx = rem - ry*REG;
            pool[r*2 + ch] = F0[(size_t)ch*VOL3 + ((lz+rz)*64 + (ly+ry))*64 + (lx+rx)];
        }
        __syncthreads();
        const float f0 = fixedv[2*cp], f1 = fixedv[2*cp+1];
        const float2* Rg = (const float2*)pool;
        for (int d = tid; d < DW3; d += NTHREADS) {
            int kx = d % 15;
            int t2 = d / 15;
            int ky = t2 % 15;
            int kz = t2 / 15;
            float tx = tT[kx], ty = tT[15+ky], tz = tT[30+kz];
            int ix0 = tI0[kx],   ix1 = tI1[kx];
            int iy0 = tI0[15+ky], iy1 = tI1[15+ky];
            int iz0 = tI0[30+kz], iz1 = tI1[30+kz];
            float wx0 = 1.0f-tx, wy0 = 1.0f-ty, wz0 = 1.0f-tz;
            int b00 = (iz0*REG+iy0)*REG, b01 = (iz0*REG+iy1)*REG;
            int b10 = (iz1*REG+iy0)*REG, b11 = (iz1*REG+iy1)*REG;
            float m0 = 0.0f, m1 = 0.0f; float w; float2 c;
            c = Rg[b00+ix0]; w = wz0*wy0*wx0; m0 = fmaf(w,c.x,m0); m1 = fmaf(w,c.y,m1);
            c = Rg[b00+ix1]; w = wz0*wy0*tx ; m0 = fmaf(w,c.x,m0); m1 = fmaf(w,c.y,m1);
            c = Rg[b01+ix0]; w = wz0*ty *wx0; m0 = fmaf(w,c.x,m0); m1 = fmaf(w,c.y,m1);
            c = Rg[b01+ix1]; w = wz0*ty *tx ; m0 = fmaf(w,c.x,m0); m1 = fmaf(w,c.y,m1);
            c = Rg[b10+ix0]; w = tz *wy0*wx0; m0 = fmaf(w,c.x,m0); m1 = fmaf(w,c.y,m1);
            c = Rg[b10+ix1]; w = tz *wy0*tx ; m0 = fmaf(w,c.x,m0); m1 = fmaf(w,c.y,m1);
            c = Rg[b11+ix0]; w = tz *ty *wx0; m0 = fmaf(w,c.x,m0); m1 = fmaf(w,c.y,m1);
            c = Rg[b11+ix1]; w = tz *ty *tx ; m0 = fmaf(w,c.x,m0); m1 = fmaf(w,c.y,m1);
            float d0 = f0 - m0, d1 = f1 - m1;
            ssdL[d] += d0*d0 + d1*d1;
        }
    }
    __syncthreads();
    float* gd = deeds + (size_t)g * DW3;
    for (int d = tid; d < DW3; d += NTHREADS) {
        float cval = a1 + a0 * ssdL[d];
        pool[d] = cval;                 // v for the filter
        gd[d] = cval;                   // keep deeds_cost for the second pass
    }
    __syncthreads();
    disp_filter(pool, tid, cost1 + (size_t)g * DW3);
}

// ---------------------------------------------------------------------------
// K3: cost2 = a4 + a2*deeds + a3*cost_avg, then displacement filter (in-place
// on the [g][d] buffer: row g is read fully into LDS before being rewritten).
// ---------------------------------------------------------------------------
__global__ __launch_bounds__(NTHREADS) void k3_second(
    const float* __restrict__ deeds, const float* avg1,
    const float* __restrict__ alpha, float* costb)
{
    __shared__ float pool[POOLSZ];
    const int tid = threadIdx.x;
    const int g = blockIdx.x;
    const float a2 = alpha[2], a3 = alpha[3], a4 = alpha[4];
    const float* dg = deeds + (size_t)g*DW3;
    const float* ag = avg1 + (size_t)g*DW3;
    for (int d = tid; d < DW3; d += NTHREADS)
        pool[d] = a4 + a2*dg[d] + a3*ag[d];
    __syncthreads();
    disp_filter(pool, tid, costb + (size_t)g*DW3);
}

// ---------------------------------------------------------------------------
// Grid-domain smoothing: per displacement 4-tile, [16][16][16] grid volume,
// separable clamped 5-tap [1,2,3,2,1]/9 per axis. Lines held in registers.
// LDS layout padded (stride 68 per 16x4 row) to avoid x-pass bank conflicts.
// In-place safe (each block owns its d-columns).
// ---------------------------------------------------------------------------
#define GPAD 68
#define GROW 1088   // 16*GPAD

__device__ __forceinline__ void smooth_line(float* buf, int base, int stride)
{
    const float w0 = 1.0f/9.0f, w1 = 2.0f/9.0f, w2 = 3.0f/9.0f;
    float r[16], o[16];
    #pragma unroll
    for (int k = 0; k < 16; ++k) r[k] = buf[base + k*stride];
    #pragma unroll
    for (int i = 0; i < 16; ++i) {
        int m2 = i < 2 ? 0 : i-2;
        int m1i = i < 1 ? 0 : i-1;
        int p1 = i > 14 ? 15 : i+1;
        int p2 = i > 13 ? 15 : i+2;
        o[i] = w0*(r[m2]+r[p2]) + w1*(r[m1i]+r[p1]) + w2*r[i];
    }
    #pragma unroll
    for (int k = 0; k < 16; ++k) buf[base + k*stride] = o[k];
}

__global__ __launch_bounds__(NTHREADS) void k_gridsmooth(
    const float* in, float* out)
{
    __shared__ float buf[256*GPAD];
    const int tid = threadIdx.x;
    const int d0 = blockIdx.x * 4;
    for (int e = tid; e < G3*4; e += NTHREADS) {
        int gi = e >> 2, dd = e & 3;
        int d = d0 + dd;
        float val = (d < DW3) ? in[(size_t)gi*DW3 + d] : 0.0f;
        buf[(gi >> 4)*GPAD + (gi & 15)*4 + dd] = val;
    }
    __syncthreads();
    // pass over gz: columns (gy,gx,dd), stride GROW
    for (int c = tid; c < 1024; c += NTHREADS)
        smooth_line(buf, (c >> 6)*GPAD + (c & 63), GROW);
    __syncthreads();
    // pass over gy: columns (gz,gx,dd), stride GPAD
    for (int c = tid; c < 1024; c += NTHREADS)
        smooth_line(buf, (c >> 6)*GROW + (c & 63), GPAD);
    __syncthreads();
    // pass over gx: columns (gz,gy,dd), stride 4
    for (int c = tid; c < 1024; c += NTHREADS) {
        int gz = c >> 6, gy = (c >> 2) & 15, dd = c & 3;
        smooth_line(buf, gz*GROW + gy*GPAD + dd, 4);
    }
    __syncthreads();
    for (int e = tid; e < G3*4; e += NTHREADS) {
        int gi = e >> 2, dd = e & 3;
        int d = d0 + dd;
        if (d < DW3) out[(size_t)gi*DW3 + d] = buf[(gi >> 4)*GPAD + (gi & 15)*4 + dd];
    }
}

// ---------------------------------------------------------------------------
// K5: row softmax over 3375 (logits = -a5*cost) + displacement expectation.
// In-place safe (row read into registers before being rewritten).
// ---------------------------------------------------------------------------
__global__ __launch_bounds__(NTHREADS) void k5_softmax(
    const float* avg2, const float* __restrict__ shift,
    const float* __restrict__ alpha, float* out_soft, float* __restrict__ out_pred)
{
    __shared__ float wmax[4];
    __shared__ float wred[4][4];
    const int tid = threadIdx.x;
    const int g = blockIdx.x;
    const int lane = tid & 63, wid = tid >> 6;
    const float a5 = alpha[5];
    const float* src = avg2 + (size_t)g*DW3;

    float L[14];
    float mx = -INFINITY;
    #pragma unroll
    for (int j = 0; j < 14; ++j) {
        int d = tid + j*NTHREADS;
        float val = (d < DW3) ? (-a5 * src[d]) : -INFINITY;
        L[j] = val;
        mx = fmaxf(mx, val);
    }
    #pragma unroll
    for (int off = 32; off > 0; off >>= 1)
        mx = fmaxf(mx, __shfl_down(mx, off));
    if (lane == 0) wmax[wid] = mx;
    __syncthreads();
    mx = fmaxf(fmaxf(wmax[0], wmax[1]), fmaxf(wmax[2], wmax[3]));

    float E[14];
    float s = 0.0f, px = 0.0f, py = 0.0f, pz = 0.0f;
    #pragma unroll
    for (int j = 0; j < 14; ++j) {
        int d = tid + j*NTHREADS;
        E[j] = 0.0f;
        if (d < DW3) {
            float e = __expf(L[j] - mx);
            E[j] = e;
            s += e;
            px = fmaf(e, shift[d*3+0], px);
            py = fmaf(e, shift[d*3+1], py);
            pz = fmaf(e, shift[d*3+2], pz);
        }
    }
    #pragma unroll
    for (int off = 32; off > 0; off >>= 1) {
        s  += __shfl_down(s, off);
        px += __shfl_down(px, off);
        py += __shfl_down(py, off);
        pz += __shfl_down(pz, off);
    }
    if (lane == 0) { wred[wid][0]=s; wred[wid][1]=px; wred[wid][2]=py; wred[wid][3]=pz; }
    __syncthreads();
    float st = wred[0][0]+wred[1][0]+wred[2][0]+wred[3][0];
    float inv = 1.0f / st;
    float* dst = out_soft + (size_t)g*DW3;
    #pragma unroll
    for (int j = 0; j < 14; ++j) {
        int d = tid + j*NTHREADS;
        if (d < DW3) dst[d] = E[j]*inv;
    }
    if (tid == 0) {
        float pxt = wred[0][1]+wred[1][1]+wred[2][1]+wred[3][1];
        float pyt = wred[0][2]+wred[1][2]+wred[2][2]+wred[3][2];
        float pzt = wred[0][3]+wred[1][3]+wred[2][3]+wred[3][3];
        out_pred[g*3+0] = pxt*inv;
        out_pred[g*3+1] = pyt*inv;
        out_pred[g*3+2] = pzt*inv;
    }
}

// ---------------------------------------------------------------------------
extern "C" void kernel_launch(void* const* d_in, const int* in_sizes, int n_in,
                              void* d_out, int out_size, void* d_ws, size_t ws_size,
                              hipStream_t stream)
{
    const float* feat00 = (const float*)d_in[0];
    const float* feat50 = (const float*)d_in[1];
    const float* grid   = (const float*)d_in[2];
    // d_in[3] = grid_size (16), d_in[4] = displacement_width (15): hardcoded
    const float* shift  = (const float*)d_in[5];
    const float* alpha  = (const float*)d_in[6];

    float* deeds = (float*)d_ws;                     // [G3][DW3] fp32 = 55.3 MB
    float* cbuf  = (float*)d_out;                    // [G3][DW3] staging in output
    float* pred  = (float*)d_out + (size_t)G3*DW3;   // [G3][3]

    k1_sample  <<<G3,        NTHREADS, 0, stream>>>(feat00, feat50, grid, alpha, deeds, cbuf);
    k_gridsmooth<<<(DW3+3)/4, NTHREADS, 0, stream>>>(cbuf, cbuf);
    k3_second  <<<G3,        NTHREADS, 0, stream>>>(deeds, cbuf, alpha, cbuf);
    k_gridsmooth<<<(DW3+3)/4, NTHREADS, 0, stream>>>(cbuf, cbuf);
    k5_softmax <<<G3,        NTHREADS, 0, stream>>>(cbuf, shift, alpha, cbuf, pred);
}

// Round 3
// 660.174 us; speedup vs baseline: 1.3748x; 1.3748x over previous
//
#include <hip/hip_runtime.h>
#include <hip/hip_fp16.h>
#include <math.h>

#define NTHREADS 256
#define G3   4096
#define DW3  3375
#define VOL  64
#define VOL3 (VOL*VOL*VOL)
#define POOL 12274   // floats; filter ping-pong peak (5415+6859); >= staging 11664
#define J14  14

#if defined(__has_builtin)
#if __has_builtin(__builtin_amdgcn_fdot2)
#define HAS_FDOT2 1
#endif
#endif

typedef _Float16 h2v __attribute__((ext_vector_type(2)));

__device__ __forceinline__ float dot2acc(__half2 a, float c) {
#ifdef HAS_FDOT2
    h2v av = __builtin_bit_cast(h2v, a);
    return __builtin_amdgcn_fdot2(av, av, c, false);
#else
    float2 af = __half22float2(a);
    return fmaf(af.x, af.x, fmaf(af.y, af.y, c));
#endif
}

// ---------------------------------------------------------------------------
// Displacement-domain filter: out = avgp3(avgp3(-maxp3(-rpad3(v))))
// = separable clamped min-3 (15->19/axis) then separable 5-tap [1,2,3,2,1]/9.
// Ping-pong inside pool[POOL] floats. Input v at pool[0..3375). Output global.
//   s1 min-x : v@0      [15][15][15] -> A@7999 [15][15][19]
//   s2 min-y : A@7999                -> B@0    [15][19][19]
//   s3 min-z : B@0                   -> C@5415 [19][19][19]
//   s4 sm-x  : C@5415                -> D@0    [19][19][15]
//   s5 sm-y  : D@0                   -> E@5415 [19][15][15]
//   s6 sm-z  : E@5415                -> gout   [15][15][15]
// ---------------------------------------------------------------------------
__device__ __forceinline__ void disp_filter(float* pool, int tid, float* gout)
{
    const float w0 = 1.0f/9.0f, w1 = 2.0f/9.0f, w2 = 3.0f/9.0f;
    float* A = pool + 7999;
    for (int e = tid; e < 15*15*19; e += NTHREADS) {
        int x = e % 19, zy = e / 19;
        int i0 = max(0,min(14,x-3)), i1 = max(0,min(14,x-2)), i2 = max(0,min(14,x-1));
        const float* row = pool + zy*15;
        A[e] = fminf(fminf(row[i0],row[i1]),row[i2]);
    }
    __syncthreads();
    float* B = pool;
    for (int e = tid; e < 15*19*19; e += NTHREADS) {
        int x = e % 19; int y = (e/19) % 19; int z = e/361;
        int i0 = max(0,min(14,y-3)), i1 = max(0,min(14,y-2)), i2 = max(0,min(14,y-1));
        const float* colb = A + z*285 + x;             // 15*19 = 285
        B[e] = fminf(fminf(colb[i0*19],colb[i1*19]),colb[i2*19]);
    }
    __syncthreads();
    float* C = pool + 5415;
    for (int e = tid; e < 19*19*19; e += NTHREADS) {
        int xy = e % 361, z = e/361;
        int i0 = max(0,min(14,z-3)), i1 = max(0,min(14,z-2)), i2 = max(0,min(14,z-1));
        const float* colb = B + xy;
        C[e] = fminf(fminf(colb[i0*361],colb[i1*361]),colb[i2*361]);
    }
    __syncthreads();
    float* D = pool;
    for (int e = tid; e < 19*19*15; e += NTHREADS) {
        int i = e % 15, zy = e/15;
        const float* row = C + zy*19 + i;
        D[e] = w0*(row[0]+row[4]) + w1*(row[1]+row[3]) + w2*row[2];
    }
    __syncthreads();
    float* E = pool + 5415;
    for (int e = tid; e < 19*15*15; e += NTHREADS) {
        int i = e % 15, j = (e/15)%15, z = e/225;
        const float* b2 = D + (z*19 + j)*15 + i;
        E[e] = w0*(b2[0]+b2[60]) + w1*(b2[15]+b2[45]) + w2*b2[30];
    }
    __syncthreads();
    for (int e = tid; e < DW3; e += NTHREADS) {
        int ji = e % 225, k = e/225;
        const float* b2 = E + k*225 + ji;
        gout[e] = w0*(b2[0]+b2[900]) + w1*(b2[225]+b2[675]) + w2*b2[450];
    }
}

// ---------------------------------------------------------------------------
// K1: per grid point — fp16-packed trilinear SSD correlation (18^3 window,
// 4 channels/pass x 2 passes, register ssd) + fused displacement filter.
// ---------------------------------------------------------------------------
__global__ __launch_bounds__(NTHREADS,3) void k1_sample(
    const float* __restrict__ feat00, const float* __restrict__ feat50,
    const float* __restrict__ grid_xyz, const float* __restrict__ alpha,
    float* __restrict__ deeds, float* __restrict__ cost1)
{
    __shared__ __align__(16) float pool[POOL];
    __shared__ int4 tabx[15], taby[15], tabz[15];
    __shared__ float fixedv[8];
    __shared__ int   loS[3];
    __shared__ float gpos[3];

    const int tid = threadIdx.x;
    const int g = blockIdx.x;

    if (tid < 3) {
        float p = (grid_xyz[g*3 + tid] + 1.0f) * 31.5f;    // voxel coords [0,63]
        int lo = (int)floorf(p) - 8;
        lo = lo < 0 ? 0 : (lo > 46 ? 46 : lo);
        loS[tid] = lo;
        gpos[tid] = p;
    }
    __syncthreads();
    if (tid < 45) {   // packed per-axis tables: {frac_bits, byteoff(i0), byteoff(i1)}
        int ax = tid / 15, k = tid - ax*15;
        float p = gpos[ax] + (1.125f*(float)k - 7.875f);
        p = fminf(fmaxf(p, 0.0f), 63.0f);
        float f = floorf(p);
        int i0 = (int)f;
        int i1 = i0 + 1 > 63 ? 63 : i0 + 1;
        int sc = (ax==0) ? 8 : (ax==1) ? 144 : 2592;       // byte strides (8B/voxel)
        int4 e;
        e.x = __float_as_int(p - f);
        e.y = (i0 - loS[ax]) * sc;
        e.z = (i1 - loS[ax]) * sc;
        e.w = 0;
        ((ax==0) ? tabx : (ax==1) ? taby : tabz)[k] = e;
    }
    if (tid < 8) {    // fixed sample from feat00 (fp32 exact)
        float px = gpos[0], py = gpos[1], pz = gpos[2];
        int x0 = (int)floorf(px), y0 = (int)floorf(py), z0 = (int)floorf(pz);
        float tx = px-(float)x0, ty = py-(float)y0, tz = pz-(float)z0;
        int x1 = x0+1>63?63:x0+1, y1 = y0+1>63?63:y0+1, z1 = z0+1>63?63:z0+1;
        const float* F = feat00 + (size_t)tid * VOL3;
        float v000=F[(z0*64+y0)*64+x0], v001=F[(z0*64+y0)*64+x1];
        float v010=F[(z0*64+y1)*64+x0], v011=F[(z0*64+y1)*64+x1];
        float v100=F[(z1*64+y0)*64+x0], v101=F[(z1*64+y0)*64+x1];
        float v110=F[(z1*64+y1)*64+x0], v111=F[(z1*64+y1)*64+x1];
        float wx0=1.0f-tx, wy0=1.0f-ty, wz0=1.0f-tz;
        fixedv[tid] =
            wz0*(wy0*(wx0*v000 + tx*v001) + ty*(wx0*v010 + tx*v011)) +
            tz *(wy0*(wx0*v100 + tx*v101) + ty*(wx0*v110 + tx*v111));
    }

    float ssd[J14];
    #pragma unroll
    for (int j = 0; j < J14; ++j) ssd[j] = 0.0f;

    for (int p = 0; p < 2; ++p) {
        __syncthreads();                         // tables ready / prev pass reads done
        const int lx = loS[0], ly = loS[1], lz = loS[2];
        const float* Fb = feat50 + (size_t)(4*p) * VOL3;
        // stage 18^3 window: 4 channels packed to 2x half2 (8B/voxel), row-wise
        for (int rw = tid; rw < 324; rw += NTHREADS) {
            int rz = rw / 18, ry = rw - rz*18;
            const float* src = Fb + ((lz+rz)*64 + (ly+ry))*64 + lx;
            uint2* dst = ((uint2*)pool) + rw*18;
            #pragma unroll 6
            for (int rx = 0; rx < 18; ++rx) {
                float c0 = src[rx];
                float c1 = src[VOL3 + rx];
                float c2 = src[2*VOL3 + rx];
                float c3 = src[3*VOL3 + rx];
                __half2 h01 = __floats2half2_rn(c0, c1);
                __half2 h23 = __floats2half2_rn(c2, c3);
                uint2 u;
                u.x = __builtin_bit_cast(unsigned, h01);
                u.y = __builtin_bit_cast(unsigned, h23);
                dst[rx] = u;
            }
        }
        __syncthreads();
        __half2 f01 = __floats2half2_rn(fixedv[4*p+0], fixedv[4*p+1]);
        __half2 f23 = __floats2half2_rn(fixedv[4*p+2], fixedv[4*p+3]);
        const char* base = (const char*)pool;
        #pragma unroll
        for (int j = 0; j < J14; ++j) {
            int d = tid + j*NTHREADS;
            if (d < DW3) {
                int kx = d % 15; int t2 = d / 15; int ky = t2 % 15; int kz = t2 / 15;
                int4 X = tabx[kx], Y = taby[ky], Z = tabz[kz];
                float tx = __int_as_float(X.x), ty = __int_as_float(Y.x), tz = __int_as_float(Z.x);
                float sx = 1.0f-tx, sy = 1.0f-ty, sz = 1.0f-tz;
                float Aw = sz*sy, Bw = sz*ty, Cw = tz*sy, Dw = tz*ty;
                int a00 = Z.y + Y.y, a01 = Z.y + Y.z, a10 = Z.z + Y.y, a11 = Z.z + Y.z;
                __half2 m01 = __floats2half2_rn(0.0f, 0.0f);
                __half2 m23 = m01;
                uint2 c;
                #define CORNER(ADDR, W) { \
                    c = *(const uint2*)(base + (ADDR)); \
                    __half2 wh = __floats2half2_rn((W), (W)); \
                    m01 = __hfma2(__builtin_bit_cast(__half2, c.x), wh, m01); \
                    m23 = __hfma2(__builtin_bit_cast(__half2, c.y), wh, m23); }
                CORNER(a00 + X.y, Aw*sx) CORNER(a00 + X.z, Aw*tx)
                CORNER(a01 + X.y, Bw*sx) CORNER(a01 + X.z, Bw*tx)
                CORNER(a10 + X.y, Cw*sx) CORNER(a10 + X.z, Cw*tx)
                CORNER(a11 + X.y, Dw*sx) CORNER(a11 + X.z, Dw*tx)
                #undef CORNER
                __half2 d01 = __hsub2(f01, m01), d23 = __hsub2(f23, m23);
                ssd[j] = dot2acc(d01, dot2acc(d23, ssd[j]));
            }
        }
    }
    const float a0 = alpha[0], a1 = alpha[1];
    __syncthreads();                             // all staging reads complete
    float* gd = deeds + (size_t)g * DW3;
    #pragma unroll
    for (int j = 0; j < J14; ++j) {
        int d = tid + j*NTHREADS;
        if (d < DW3) {
            float cv = fmaf(a0, ssd[j], a1);
            pool[d] = cv;
            gd[d] = cv;
        }
    }
    __syncthreads();
    disp_filter(pool, tid, cost1 + (size_t)g * DW3);
}

// ---------------------------------------------------------------------------
// K3: cost2 = a4 + a2*deeds + a3*cost_avg, then displacement filter (in-place)
// ---------------------------------------------------------------------------
__global__ __launch_bounds__(NTHREADS,3) void k3_second(
    const float* __restrict__ deeds, const float* avg1,
    const float* __restrict__ alpha, float* costb)
{
    __shared__ __align__(16) float pool[POOL];
    const int tid = threadIdx.x;
    const int g = blockIdx.x;
    const float a2 = alpha[2], a3 = alpha[3], a4 = alpha[4];
    const float* dg = deeds + (size_t)g*DW3;
    const float* ag = avg1 + (size_t)g*DW3;
    for (int d = tid; d < DW3; d += NTHREADS)
        pool[d] = a4 + a2*dg[d] + a3*ag[d];
    __syncthreads();
    disp_filter(pool, tid, costb + (size_t)g*DW3);
}

// ---------------------------------------------------------------------------
// Grid-domain smoothing (separable clamped 5-tap [1,2,3,2,1]/9 over 16^3),
// split into two fully-coalesced kernels over 16-d line tiles.
// ---------------------------------------------------------------------------
#define GSP 17

__device__ __forceinline__ void smooth16(const float* r, float* o)
{
    const float w0 = 1.0f/9.0f, w1 = 2.0f/9.0f, w2 = 3.0f/9.0f;
    #pragma unroll
    for (int i = 0; i < 16; ++i) {
        int m2 = i<2?0:i-2, m1 = i<1?0:i-1, p1 = i>14?15:i+1, p2 = i>13?15:i+2;
        o[i] = w0*(r[m2]+r[p2]) + w1*(r[m1]+r[p1]) + w2*r[i];
    }
}

// x & y passes: block = (d-tile 16, gz-slab). LDS [gy][gx][17].
__global__ __launch_bounds__(NTHREADS) void k_smooth_xy(float* buf)
{
    __shared__ float t[16*16*GSP];
    const int tid = threadIdx.x;
    const int d0 = blockIdx.x * 16;
    const int gz = blockIdx.y;
    const int dd = tid & 15, sub = tid >> 4;
    const int d = d0 + dd;
    const bool dok = d < DW3;
    for (int it = 0; it < 16; ++it) {
        int gyx = it*16 + sub;
        t[gyx*GSP + dd] = dok ? buf[(size_t)(gz*256 + gyx)*DW3 + d] : 0.0f;
    }
    __syncthreads();
    {   // x-pass: thread (gy=sub, dd), line over gx
        float r[16], o[16];
        int b = sub*(16*GSP) + dd;
        #pragma unroll
        for (int k = 0; k < 16; ++k) r[k] = t[b + k*GSP];
        smooth16(r, o);
        #pragma unroll
        for (int k = 0; k < 16; ++k) t[b + k*GSP] = o[k];
    }
    __syncthreads();
    {   // y-pass: thread (gx=sub, dd), line over gy
        float r[16], o[16];
        int b = sub*GSP + dd;
        #pragma unroll
        for (int k = 0; k < 16; ++k) r[k] = t[b + k*(16*GSP)];
        smooth16(r, o);
        #pragma unroll
        for (int k = 0; k < 16; ++k) t[b + k*(16*GSP)] = o[k];
    }
    __syncthreads();
    for (int it = 0; it < 16; ++it) {
        int gyx = it*16 + sub;
        if (dok) buf[(size_t)(gz*256 + gyx)*DW3 + d] = t[gyx*GSP + dd];
    }
}

// z pass: block = (d-tile 16, 32-gyx chunk). LDS [gyx32][gz16][17].
__global__ __launch_bounds__(NTHREADS) void k_smooth_z(float* buf)
{
    __shared__ float t[32*16*GSP];
    const int tid = threadIdx.x;
    const int d0 = blockIdx.x * 16;
    const int gyx0 = blockIdx.y * 32;
    const int dd = tid & 15, sub = tid >> 4;
    const int d = d0 + dd;
    const bool dok = d < DW3;
    for (int it = 0; it < 32; ++it) {
        int p = it*16 + sub;            // p = gyxl*16 + gz
        int gyxl = p >> 4, gz = p & 15;
        t[(gyxl*16 + gz)*GSP + dd] = dok ? buf[(size_t)(gz*256 + gyx0 + gyxl)*DW3 + d] : 0.0f;
    }
    __syncthreads();
    for (int c = tid; c < 512; c += NTHREADS) {   // z lines: (gyxl, dd)
        int gyxl = c >> 4, ddl = c & 15;
        float r[16], o[16];
        int b = gyxl*(16*GSP) + ddl;
        #pragma unroll
        for (int k = 0; k < 16; ++k) r[k] = t[b + k*GSP];
        smooth16(r, o);
        #pragma unroll
        for (int k = 0; k < 16; ++k) t[b + k*GSP] = o[k];
    }
    __syncthreads();
    for (int it = 0; it < 32; ++it) {
        int p = it*16 + sub;
        int gyxl = p >> 4, gz = p & 15;
        if (dok) buf[(size_t)(gz*256 + gyx0 + gyxl)*DW3 + d] = t[(gyxl*16 + gz)*GSP + dd];
    }
}

// ---------------------------------------------------------------------------
// K5: row softmax over 3375 (logits = -a5*cost) + displacement expectation.
// ---------------------------------------------------------------------------
__global__ __launch_bounds__(NTHREADS) void k5_softmax(
    const float* avg2, const float* __restrict__ shift,
    const float* __restrict__ alpha, float* out_soft, float* __restrict__ out_pred)
{
    __shared__ float wmax[4];
    __shared__ float wred[4][4];
    const int tid = threadIdx.x;
    const int g = blockIdx.x;
    const int lane = tid & 63, wid = tid >> 6;
    const float a5 = alpha[5];
    const float* src = avg2 + (size_t)g*DW3;

    float L[J14];
    float mx = -INFINITY;
    #pragma unroll
    for (int j = 0; j < J14; ++j) {
        int d = tid + j*NTHREADS;
        float val = (d < DW3) ? (-a5 * src[d]) : -INFINITY;
        L[j] = val;
        mx = fmaxf(mx, val);
    }
    #pragma unroll
    for (int off = 32; off > 0; off >>= 1)
        mx = fmaxf(mx, __shfl_down(mx, off));
    if (lane == 0) wmax[wid] = mx;
    __syncthreads();
    mx = fmaxf(fmaxf(wmax[0], wmax[1]), fmaxf(wmax[2], wmax[3]));

    float E[J14];
    float s = 0.0f, px = 0.0f, py = 0.0f, pz = 0.0f;
    #pragma unroll
    for (int j = 0; j < J14; ++j) {
        int d = tid + j*NTHREADS;
        E[j] = 0.0f;
        if (d < DW3) {
            float e = __expf(L[j] - mx);
            E[j] = e;
            s += e;
            px = fmaf(e, shift[d*3+0], px);
            py = fmaf(e, shift[d*3+1], py);
            pz = fmaf(e, shift[d*3+2], pz);
        }
    }
    #pragma unroll
    for (int off = 32; off > 0; off >>= 1) {
        s  += __shfl_down(s, off);
        px += __shfl_down(px, off);
        py += __shfl_down(py, off);
        pz += __shfl_down(pz, off);
    }
    if (lane == 0) { wred[wid][0]=s; wred[wid][1]=px; wred[wid][2]=py; wred[wid][3]=pz; }
    __syncthreads();
    float st = wred[0][0]+wred[1][0]+wred[2][0]+wred[3][0];
    float inv = 1.0f / st;
    float* dst = out_soft + (size_t)g*DW3;
    #pragma unroll
    for (int j = 0; j < J14; ++j) {
        int d = tid + j*NTHREADS;
        if (d < DW3) dst[d] = E[j]*inv;
    }
    if (tid == 0) {
        out_pred[g*3+0] = (wred[0][1]+wred[1][1]+wred[2][1]+wred[3][1])*inv;
        out_pred[g*3+1] = (wred[0][2]+wred[1][2]+wred[2][2]+wred[3][2])*inv;
        out_pred[g*3+2] = (wred[0][3]+wred[1][3]+wred[2][3]+wred[3][3])*inv;
    }
}

// ---------------------------------------------------------------------------
extern "C" void kernel_launch(void* const* d_in, const int* in_sizes, int n_in,
                              void* d_out, int out_size, void* d_ws, size_t ws_size,
                              hipStream_t stream)
{
    const float* feat00 = (const float*)d_in[0];
    const float* feat50 = (const float*)d_in[1];
    const float* grid   = (const float*)d_in[2];
    const float* shift  = (const float*)d_in[5];
    const float* alpha  = (const float*)d_in[6];

    float* deeds = (float*)d_ws;                     // [G3][DW3] fp32 = 55.3 MB
    float* cbuf  = (float*)d_out;                    // [G3][DW3] staging in output
    float* pred  = (float*)d_out + (size_t)G3*DW3;   // [G3][3]

    dim3 gxy(211, 16), gz(211, 8);
    k1_sample <<<G3, NTHREADS, 0, stream>>>(feat00, feat50, grid, alpha, deeds, cbuf);
    k_smooth_xy<<<gxy, NTHREADS, 0, stream>>>(cbuf);
    k_smooth_z <<<gz,  NTHREADS, 0, stream>>>(cbuf);
    k3_second <<<G3, NTHREADS, 0, stream>>>(deeds, cbuf, alpha, cbuf);
    k_smooth_xy<<<gxy, NTHREADS, 0, stream>>>(cbuf);
    k_smooth_z <<<gz,  NTHREADS, 0, stream>>>(cbuf);
    k5_softmax <<<G3, NTHREADS, 0, stream>>>(cbuf, shift, alpha, cbuf, pred);
}

// Round 9
// 496.677 us; speedup vs baseline: 1.8274x; 1.3292x over previous
//
#include <hip/hip_runtime.h>
#include <hip/hip_fp16.h>
#include <math.h>

#define NTHREADS 256
#define G3   4096
#define DW3  3375
#define VOL  64
#define VOL3 (VOL*VOL*VOL)
#define NSL  10          // z-slices per chunk
#define POOLF 6859       // shared pool floats (filter peak 19^3); staging 3240*2=6480 fits
#define GSP  17

#if defined(__has_builtin)
#if __has_builtin(__builtin_amdgcn_fdot2)
#define HAS_FDOT2 1
#endif
#endif

typedef unsigned int uint;
typedef _Float16 h2v __attribute__((ext_vector_type(2)));

__device__ __forceinline__ float dot2acc(__half2 a, float c) {
#ifdef HAS_FDOT2
    h2v av = __builtin_bit_cast(h2v, a);
    return __builtin_amdgcn_fdot2(av, av, c, false);
#else
    float2 af = __half22float2(a);
    return fmaf(af.x, af.x, fmaf(af.y, af.y, c));
#endif
}

// ---------------------------------------------------------------------------
// Prepack feat50 into 2 channel-packed fp16x4 volumes: P[p][z][y][x] = uint2
// (ch 4p..4p+3). 8B/voxel, coalesced staging loads in k1.
// ---------------------------------------------------------------------------
__global__ __launch_bounds__(NTHREADS) void k_prepack(
    const float* __restrict__ f, uint2* __restrict__ P)
{
    int v = blockIdx.x * NTHREADS + threadIdx.x;      // grid = VOL3/256 exact
    float c0 = f[v],        c1 = f[VOL3 + v],   c2 = f[2*VOL3 + v], c3 = f[3*VOL3 + v];
    float c4 = f[4*VOL3+v], c5 = f[5*VOL3 + v], c6 = f[6*VOL3 + v], c7 = f[7*VOL3 + v];
    uint2 a, b;
    a.x = __builtin_bit_cast(uint, __floats2half2_rn(c0, c1));
    a.y = __builtin_bit_cast(uint, __floats2half2_rn(c2, c3));
    b.x = __builtin_bit_cast(uint, __floats2half2_rn(c4, c5));
    b.y = __builtin_bit_cast(uint, __floats2half2_rn(c6, c7));
    P[v] = a;
    P[VOL3 + v] = b;
}

// ---------------------------------------------------------------------------
// Displacement-domain filter, register-line version (27.4 KB LDS):
// out = avgp3(avgp3(-maxp3(-rpad3(v)))) = separable clamped min-3 (15->19)
// then separable 5-tap [1,2,3,2,1]/9 (19->15). In-place ping-pong in pool.
// ---------------------------------------------------------------------------
__device__ __forceinline__ void disp_filter_reg(float* pool, int tid, float* gout)
{
    const float w0 = 1.0f/9.0f, w1 = 2.0f/9.0f, w2 = 3.0f/9.0f;
    // s1: min over x. 225 lines (z,y). in [225][15] -> out [225][19]
    {
        float r[15];
        if (tid < 225) {
            #pragma unroll
            for (int i = 0; i < 15; ++i) r[i] = pool[tid*15 + i];
        }
        __syncthreads();
        if (tid < 225) {
            #pragma unroll
            for (int x = 0; x < 19; ++x) {
                const int i0 = (x-3) < 0 ? 0 : ((x-3) > 14 ? 14 : (x-3));
                const int i1 = (x-2) < 0 ? 0 : ((x-2) > 14 ? 14 : (x-2));
                const int i2 = (x-1) < 0 ? 0 : ((x-1) > 14 ? 14 : (x-1));
                pool[tid*19 + x] = fminf(fminf(r[i0], r[i1]), r[i2]);
            }
        }
        __syncthreads();
    }
    // s2: min over y. 285 lines (z,x). in [z*15+y][19]+x -> out [15z][19y][19x]
    {
        float a[15], b[15];
        int L1 = tid + 256;
        int z0 = tid/19, x0 = tid - z0*19;
        int z1 = L1/19,  x1 = L1 - z1*19;
        bool v0 = tid < 285, v1 = L1 < 285;
        if (v0) {
            #pragma unroll
            for (int y = 0; y < 15; ++y) a[y] = pool[(z0*15 + y)*19 + x0];
        }
        if (v1) {
            #pragma unroll
            for (int y = 0; y < 15; ++y) b[y] = pool[(z1*15 + y)*19 + x1];
        }
        __syncthreads();
        #pragma unroll
        for (int y = 0; y < 19; ++y) {
            const int i0 = (y-3) < 0 ? 0 : ((y-3) > 14 ? 14 : (y-3));
            const int i1 = (y-2) < 0 ? 0 : ((y-2) > 14 ? 14 : (y-2));
            const int i2 = (y-1) < 0 ? 0 : ((y-1) > 14 ? 14 : (y-1));
            if (v0) pool[z0*361 + y*19 + x0] = fminf(fminf(a[i0], a[i1]), a[i2]);
            if (v1) pool[z1*361 + y*19 + x1] = fminf(fminf(b[i0], b[i1]), b[i2]);
        }
        __syncthreads();
    }
    // s3: min over z. 361 lines (yx). in [15][361] -> out [19][361]
    {
        float a[15], b[15];
        int L1 = tid + 256;
        bool v1 = L1 < 361;
        {
            #pragma unroll
            for (int z = 0; z < 15; ++z) a[z] = pool[z*361 + tid];
        }
        if (v1) {
            #pragma unroll
            for (int z = 0; z < 15; ++z) b[z] = pool[z*361 + L1];
        }
        __syncthreads();
        #pragma unroll
        for (int z = 0; z < 19; ++z) {
            const int i0 = (z-3) < 0 ? 0 : ((z-3) > 14 ? 14 : (z-3));
            const int i1 = (z-2) < 0 ? 0 : ((z-2) > 14 ? 14 : (z-2));
            const int i2 = (z-1) < 0 ? 0 : ((z-1) > 14 ? 14 : (z-1));
            pool[z*361 + tid] = fminf(fminf(a[i0], a[i1]), a[i2]);
            if (v1) pool[z*361 + L1] = fminf(fminf(b[i0], b[i1]), b[i2]);
        }
        __syncthreads();
    }
    // s4: smooth over x. 361 lines (zy). in [361][19] -> out [361][15]
    {
        float a[19], b[19];
        int L1 = tid + 256;
        bool v1 = L1 < 361;
        #pragma unroll
        for (int x = 0; x < 19; ++x) a[x] = pool[tid*19 + x];
        if (v1) {
            #pragma unroll
            for (int x = 0; x < 19; ++x) b[x] = pool[L1*19 + x];
        }
        __syncthreads();
        #pragma unroll
        for (int i = 0; i < 15; ++i) {
            pool[tid*15 + i] = w0*(a[i]+a[i+4]) + w1*(a[i+1]+a[i+3]) + w2*a[i+2];
            if (v1) pool[L1*15 + i] = w0*(b[i]+b[i+4]) + w1*(b[i+1]+b[i+3]) + w2*b[i+2];
        }
        __syncthreads();
    }
    // s5: smooth over y. 285 lines (z,x). in [z*19+y][15]+x -> out [z*15+y][15]+x
    {
        float a[19], b[19];
        int L1 = tid + 256;
        int z0 = tid/15, x0 = tid - z0*15;
        int z1 = L1/15,  x1 = L1 - z1*15;
        bool v0 = tid < 285, v1 = L1 < 285;
        if (v0) {
            #pragma unroll
            for (int y = 0; y < 19; ++y) a[y] = pool[(z0*19 + y)*15 + x0];
        }
        if (v1) {
            #pragma unroll
            for (int y = 0; y < 19; ++y) b[y] = pool[(z1*19 + y)*15 + x1];
        }
        __syncthreads();
        #pragma unroll
        for (int i = 0; i < 15; ++i) {
            if (v0) pool[(z0*15 + i)*15 + x0] = w0*(a[i]+a[i+4]) + w1*(a[i+1]+a[i+3]) + w2*a[i+2];
            if (v1) pool[(z1*15 + i)*15 + x1] = w0*(b[i]+b[i+4]) + w1*(b[i+1]+b[i+3]) + w2*b[i+2];
        }
        __syncthreads();
    }
    // s6: smooth over z. 225 lines (yx). in [19][225] -> out [15][225], then copy out.
    {
        float a[19];
        if (tid < 225) {
            #pragma unroll
            for (int z = 0; z < 19; ++z) a[z] = pool[z*225 + tid];
        }
        __syncthreads();
        if (tid < 225) {
            #pragma unroll
            for (int i = 0; i < 15; ++i)
                pool[i*225 + tid] = w0*(a[i]+a[i+4]) + w1*(a[i+1]+a[i+3]) + w2*a[i+2];
        }
        __syncthreads();
        for (int e = tid; e < DW3; e += NTHREADS) gout[e] = pool[e];
    }
}

// ---------------------------------------------------------------------------
// K1: per grid point — packed-fp16 trilinear SSD (2 ch-groups x 2 z-chunks,
// 10x18x18 staged windows, register ssd) + fused register-line filter.
// ---------------------------------------------------------------------------
__global__ __launch_bounds__(NTHREADS,4) void k1_sample(
    const float* __restrict__ feat00, const uint2* __restrict__ P,
    const float* __restrict__ grid_xyz, const float* __restrict__ alpha,
    __half* __restrict__ deeds, float* __restrict__ cost1)
{
    __shared__ __align__(16) float pool[POOLF];
    __shared__ int4 tabx[15], taby[15], tabz[15];
    __shared__ float fixedv[8];
    __shared__ int   loS[2];     // x, y window base
    __shared__ int   lozS[2];    // z base per chunk
    __shared__ float gpos[3];

    const int tid = threadIdx.x;
    const int g = blockIdx.x;

    if (tid < 3) gpos[tid] = (grid_xyz[g*3 + tid] + 1.0f) * 31.5f;   // [0,63]
    __syncthreads();
    if (tid < 2) {
        int lo = (int)floorf(gpos[tid]) - 8;
        loS[tid] = lo < 0 ? 0 : (lo > 46 ? 46 : lo);
    } else if (tid < 4) {
        int k = (tid - 2) * 8;                    // k=0 -> chunk0, k=8 -> chunk1
        float pz = gpos[2] + (1.125f*(float)k - 7.875f);
        pz = fminf(fmaxf(pz, 0.0f), 63.0f);
        lozS[tid-2] = (int)floorf(pz);
    }
    __syncthreads();
    if (tid < 45) {   // per-axis tables {frac_bits, byteoff(i0), byteoff(i1)}
        int ax = tid / 15, k = tid - ax*15;
        float p = gpos[ax] + (1.125f*(float)k - 7.875f);
        p = fminf(fmaxf(p, 0.0f), 63.0f);
        float f = floorf(p);
        int i0 = (int)f;
        int i1 = i0 + 1 > 63 ? 63 : i0 + 1;
        int lo = (ax == 2) ? lozS[k < 8 ? 0 : 1] : loS[ax];
        int sc = (ax == 0) ? 8 : (ax == 1) ? 144 : 2592;   // byte strides (8B/voxel)
        int4 e;
        e.x = __float_as_int(p - f);
        e.y = (i0 - lo) * sc;
        e.z = (i1 - lo) * sc;
        e.w = 0;
        ((ax == 0) ? tabx : (ax == 1) ? taby : tabz)[k] = e;
    }
    if (tid < 8) {    // fixed sample from feat00 (fp32 exact)
        float px = gpos[0], py = gpos[1], pz = gpos[2];
        int x0 = (int)floorf(px), y0 = (int)floorf(py), z0 = (int)floorf(pz);
        float tx = px-(float)x0, ty = py-(float)y0, tz = pz-(float)z0;
        int x1 = x0+1>63?63:x0+1, y1 = y0+1>63?63:y0+1, z1 = z0+1>63?63:z0+1;
        const float* F = feat00 + (size_t)tid * VOL3;
        float v000=F[(z0*64+y0)*64+x0], v001=F[(z0*64+y0)*64+x1];
        float v010=F[(z0*64+y1)*64+x0], v011=F[(z0*64+y1)*64+x1];
        float v100=F[(z1*64+y0)*64+x0], v101=F[(z1*64+y0)*64+x1];
        float v110=F[(z1*64+y1)*64+x0], v111=F[(z1*64+y1)*64+x1];
        float wx0=1.0f-tx, wy0=1.0f-ty, wz0=1.0f-tz;
        fixedv[tid] =
            wz0*(wy0*(wx0*v000 + tx*v001) + ty*(wx0*v010 + tx*v011)) +
            tz *(wy0*(wx0*v100 + tx*v101) + ty*(wx0*v110 + tx*v111));
    }
    // RACE FIX (R8): fixedv is read by ALL threads at the p-loop top below;
    // without this barrier, waves 1-3 could read stale LDS before wave 0's
    // tid<8 write (R5/R6 pred error ~1e-2, timing-dependent).
    __syncthreads();

    float s0[8], s1[7];
    #pragma unroll
    for (int j = 0; j < 8; ++j) s0[j] = 0.0f;
    #pragma unroll
    for (int j = 0; j < 7; ++j) s1[j] = 0.0f;

    const __half2 hz = __floats2half2_rn(0.0f, 0.0f);

    #define CORNER(ADDR, W) { \
        uint2 cc = *(const uint2*)(base + (ADDR)); \
        __half2 wh = __floats2half2_rn((W), (W)); \
        m01 = __hfma2(__builtin_bit_cast(__half2, cc.x), wh, m01); \
        m23 = __hfma2(__builtin_bit_cast(__half2, cc.y), wh, m23); }

    #define SAMPLE(DD, ACC) { \
        int kx = (DD) % 15; int t2 = (DD) / 15; int ky = t2 % 15; int kz = t2 / 15; \
        int4 X = tabx[kx]; int4 Y = taby[ky]; int4 Z = tabz[kz]; \
        float tx = __int_as_float(X.x), ty = __int_as_float(Y.x), tz = __int_as_float(Z.x); \
        float sx = 1.0f-tx, sy = 1.0f-ty, sz = 1.0f-tz; \
        float Aw = sz*sy, Bw = sz*ty, Cw = tz*sy, Dw = tz*ty; \
        int a00 = Z.y+Y.y, a01 = Z.y+Y.z, a10 = Z.z+Y.y, a11 = Z.z+Y.z; \
        __half2 m01 = hz, m23 = hz; \
        CORNER(a00+X.y, Aw*sx) CORNER(a00+X.z, Aw*tx) \
        CORNER(a01+X.y, Bw*sx) CORNER(a01+X.z, Bw*tx) \
        CORNER(a10+X.y, Cw*sx) CORNER(a10+X.z, Cw*tx) \
        CORNER(a11+X.y, Dw*sx) CORNER(a11+X.z, Dw*tx) \
        __half2 d01 = __hsub2(f01, m01), d23 = __hsub2(f23, m23); \
        ACC = dot2acc(d01, dot2acc(d23, ACC)); }

    for (int p = 0; p < 2; ++p) {
        const uint2* Pv = P + (size_t)p * VOL3;
        const int lx = loS[0], ly = loS[1];
        __half2 f01 = __floats2half2_rn(fixedv[4*p+0], fixedv[4*p+1]);
        __half2 f23 = __floats2half2_rn(fixedv[4*p+2], fixedv[4*p+3]);
        for (int c = 0; c < 2; ++c) {
            __syncthreads();                      // prior pool reads done
            const int lz = lozS[c];
            for (int e = tid; e < NSL*18*18; e += NTHREADS) {    // 3240 voxels
                int rz = e / 324; int rem = e - rz*324; int ry = rem / 18; int rx = rem - ry*18;
                int zz = lz + rz; zz = zz > 63 ? 63 : zz;
                ((uint2*)pool)[e] = Pv[(zz*64 + (ly+ry))*64 + (lx+rx)];
            }
            __syncthreads();
            const char* base = (const char*)pool;
            if (c == 0) {
                #pragma unroll
                for (int j = 0; j < 8; ++j) {
                    int d = tid + j*NTHREADS;
                    if (d < 1800) SAMPLE(d, s0[j])
                }
            } else {
                #pragma unroll
                for (int j = 0; j < 7; ++j) {
                    int d = 1800 + tid + j*NTHREADS;
                    if (d < DW3) SAMPLE(d, s1[j])
                }
            }
        }
    }
    #undef SAMPLE
    #undef CORNER

    const float a0 = alpha[0], a1 = alpha[1];
    __syncthreads();                              // staging reads complete
    __half* gd = deeds + (size_t)g * DW3;
    #pragma unroll
    for (int j = 0; j < 8; ++j) {
        int d = tid + j*NTHREADS;
        if (d < 1800) { float cv = fmaf(a0, s0[j], a1); gd[d] = __float2half(cv); pool[d] = cv; }
    }
    #pragma unroll
    for (int j = 0; j < 7; ++j) {
        int d = 1800 + tid + j*NTHREADS;
        if (d < DW3) { float cv = fmaf(a0, s1[j], a1); gd[d] = __float2half(cv); pool[d] = cv; }
    }
    __syncthreads();
    disp_filter_reg(pool, tid, cost1 + (size_t)g * DW3);
}

// ---------------------------------------------------------------------------
// K3: cost2 = a4 + a2*deeds + a3*avg1, then displacement filter (in-place on
// the fp32 cbuf: row g fully read before rewritten).
// ---------------------------------------------------------------------------
__global__ __launch_bounds__(NTHREADS,4) void k3_second(
    const __half* __restrict__ deeds, const float* avg1,
    const float* __restrict__ alpha, float* costb)
{
    __shared__ __align__(16) float pool[POOLF];
    const int tid = threadIdx.x;
    const int g = blockIdx.x;
    const float a2 = alpha[2], a3 = alpha[3], a4 = alpha[4];
    const __half* dg = deeds + (size_t)g*DW3;
    const float* ag = avg1 + (size_t)g*DW3;
    for (int d = tid; d < DW3; d += NTHREADS)
        pool[d] = a4 + a2*__half2float(dg[d]) + a3*ag[d];
    __syncthreads();
    disp_filter_reg(pool, tid, costb + (size_t)g*DW3);
}

// ---------------------------------------------------------------------------
// Grid-domain smoothing (separable clamped 5-tap [1,2,3,2,1]/9 over 16^3),
// two coalesced kernels over 16-d line tiles; fp32.
// ---------------------------------------------------------------------------
__device__ __forceinline__ void smooth16(const float* r, float* o)
{
    const float w0 = 1.0f/9.0f, w1 = 2.0f/9.0f, w2 = 3.0f/9.0f;
    #pragma unroll
    for (int i = 0; i < 16; ++i) {
        const int m2 = i<2?0:i-2, m1 = i<1?0:i-1, p1 = i>14?15:i+1, p2 = i>13?15:i+2;
        o[i] = w0*(r[m2]+r[p2]) + w1*(r[m1]+r[p1]) + w2*r[i];
    }
}

__global__ __launch_bounds__(NTHREADS) void k_smooth_xy(float* buf)
{
    __shared__ float t[16*16*GSP];
    const int tid = threadIdx.x;
    const int d0 = blockIdx.x * 16;
    const int gz = blockIdx.y;
    const int dd = tid & 15, sub = tid >> 4;
    const int d = d0 + dd;
    const bool dok = d < DW3;
    for (int it = 0; it < 16; ++it) {
        int gyx = it*16 + sub;
        t[gyx*GSP + dd] = dok ? buf[(size_t)(gz*256 + gyx)*DW3 + d] : 0.0f;
    }
    __syncthreads();
    {   // x-pass: thread (gy=sub, dd)
        float r[16], o[16];
        int b = sub*(16*GSP) + dd;
        #pragma unroll
        for (int k = 0; k < 16; ++k) r[k] = t[b + k*GSP];
        smooth16(r, o);
        #pragma unroll
        for (int k = 0; k < 16; ++k) t[b + k*GSP] = o[k];
    }
    __syncthreads();
    {   // y-pass: thread (gx=sub, dd)
        float r[16], o[16];
        int b = sub*GSP + dd;
        #pragma unroll
        for (int k = 0; k < 16; ++k) r[k] = t[b + k*(16*GSP)];
        smooth16(r, o);
        #pragma unroll
        for (int k = 0; k < 16; ++k) t[b + k*(16*GSP)] = o[k];
    }
    __syncthreads();
    for (int it = 0; it < 16; ++it) {
        int gyx = it*16 + sub;
        if (dok) buf[(size_t)(gz*256 + gyx)*DW3 + d] = t[gyx*GSP + dd];
    }
}

__global__ __launch_bounds__(NTHREADS) void k_smooth_z(float* buf)
{
    __shared__ float t[32*16*GSP];
    const int tid = threadIdx.x;
    const int d0 = blockIdx.x * 16;
    const int gyx0 = blockIdx.y * 32;
    const int dd = tid & 15, sub = tid >> 4;
    const int d = d0 + dd;
    const bool dok = d < DW3;
    for (int it = 0; it < 32; ++it) {
        int p = it*16 + sub;
        int gyxl = p >> 4, gz = p & 15;
        t[(gyxl*16 + gz)*GSP + dd] = dok ? buf[(size_t)(gz*256 + gyx0 + gyxl)*DW3 + d] : 0.0f;
    }
    __syncthreads();
    for (int c = tid; c < 512; c += NTHREADS) {
        int gyxl = c >> 4, ddl = c & 15;
        float r[16], o[16];
        int b = gyxl*(16*GSP) + ddl;
        #pragma unroll
        for (int k = 0; k < 16; ++k) r[k] = t[b + k*GSP];
        smooth16(r, o);
        #pragma unroll
        for (int k = 0; k < 16; ++k) t[b + k*GSP] = o[k];
    }
    __syncthreads();
    for (int it = 0; it < 32; ++it) {
        int p = it*16 + sub;
        int gyxl = p >> 4, gz = p & 15;
        if (dok) buf[(size_t)(gz*256 + gyx0 + gyxl)*DW3 + d] = t[(gyxl*16 + gz)*GSP + dd];
    }
}

// ---------------------------------------------------------------------------
// K5: row softmax over 3375 (logits = -a5*cost) + displacement expectation.
// ---------------------------------------------------------------------------
#define J14 14
__global__ __launch_bounds__(NTHREADS) void k5_softmax(
    const float* avg2, const float* __restrict__ shift,
    const float* __restrict__ alpha, float* __restrict__ out_soft,
    float* __restrict__ out_pred)
{
    __shared__ float wmax[4];
    __shared__ float wred[4][4];
    const int tid = threadIdx.x;
    const int g = blockIdx.x;
    const int lane = tid & 63, wid = tid >> 6;
    const float a5 = alpha[5];
    const float* src = avg2 + (size_t)g*DW3;

    float L[J14];
    float mx = -INFINITY;
    #pragma unroll
    for (int j = 0; j < J14; ++j) {
        int d = tid + j*NTHREADS;
        float val = (d < DW3) ? (-a5 * src[d]) : -INFINITY;
        L[j] = val;
        mx = fmaxf(mx, val);
    }
    #pragma unroll
    for (int off = 32; off > 0; off >>= 1)
        mx = fmaxf(mx, __shfl_down(mx, off));
    if (lane == 0) wmax[wid] = mx;
    __syncthreads();
    mx = fmaxf(fmaxf(wmax[0], wmax[1]), fmaxf(wmax[2], wmax[3]));

    float E[J14];
    float s = 0.0f, px = 0.0f, py = 0.0f, pz = 0.0f;
    #pragma unroll
    for (int j = 0; j < J14; ++j) {
        int d = tid + j*NTHREADS;
        E[j] = 0.0f;
        if (d < DW3) {
            float e = __expf(L[j] - mx);
            E[j] = e;
            s += e;
            px = fmaf(e, shift[d*3+0], px);
            py = fmaf(e, shift[d*3+1], py);
            pz = fmaf(e, shift[d*3+2], pz);
        }
    }
    #pragma unroll
    for (int off = 32; off > 0; off >>= 1) {
        s  += __shfl_down(s, off);
        px += __shfl_down(px, off);
        py += __shfl_down(py, off);
        pz += __shfl_down(pz, off);
    }
    if (lane == 0) { wred[wid][0]=s; wred[wid][1]=px; wred[wid][2]=py; wred[wid][3]=pz; }
    __syncthreads();
    float st = wred[0][0]+wred[1][0]+wred[2][0]+wred[3][0];
    float inv = 1.0f / st;
    float* dst = out_soft + (size_t)g*DW3;
    #pragma unroll
    for (int j = 0; j < J14; ++j) {
        int d = tid + j*NTHREADS;
        if (d < DW3) dst[d] = E[j]*inv;
    }
    if (tid == 0) {
        out_pred[g*3+0] = (wred[0][1]+wred[1][1]+wred[2][1]+wred[3][1])*inv;
        out_pred[g*3+1] = (wred[0][2]+wred[1][2]+wred[2][2]+wred[3][2])*inv;
        out_pred[g*3+2] = (wred[0][3]+wred[1][3]+wred[2][3]+wred[3][3])*inv;
    }
}

// ---------------------------------------------------------------------------
// Memory plan:
//   d_ws : deeds fp16 [G3*DW3] (27.65 MB) | P packed uint2 [2*VOL3] (4 MB)
//   d_out: cbuf fp32 [G3*DW3] (cost1/avg1/cost2/avg2 staging, finally
//          overwritten in-place by k5's cost_soft) | pred [G3*3]
// ---------------------------------------------------------------------------
extern "C" void kernel_launch(void* const* d_in, const int* in_sizes, int n_in,
                              void* d_out, int out_size, void* d_ws, size_t ws_size,
                              hipStream_t stream)
{
    const float* feat00 = (const float*)d_in[0];
    const float* feat50 = (const float*)d_in[1];
    const float* grid   = (const float*)d_in[2];
    const float* shift  = (const float*)d_in[5];
    const float* alpha  = (const float*)d_in[6];

    __half* deeds = (__half*)d_ws;
    uint2*  P     = (uint2*)((char*)d_ws + (size_t)G3*DW3*sizeof(__half));
    float*  cbuf  = (float*)d_out;
    float*  soft  = (float*)d_out;
    float*  pred  = (float*)d_out + (size_t)G3*DW3;

    dim3 gxy(211, 16), gz(211, 8);
    k_prepack <<<VOL3/NTHREADS, NTHREADS, 0, stream>>>(feat50, P);
    k1_sample <<<G3, NTHREADS, 0, stream>>>(feat00, P, grid, alpha, deeds, cbuf);
    k_smooth_xy<<<gxy, NTHREADS, 0, stream>>>(cbuf);
    k_smooth_z <<<gz,  NTHREADS, 0, stream>>>(cbuf);
    k3_second <<<G3, NTHREADS, 0, stream>>>(deeds, cbuf, alpha, cbuf);
    k_smooth_xy<<<gxy, NTHREADS, 0, stream>>>(cbuf);
    k_smooth_z <<<gz,  NTHREADS, 0, stream>>>(cbuf);
    k5_softmax <<<G3, NTHREADS, 0, stream>>>(cbuf, shift, alpha, soft, pred);
}

// Round 10
// 471.182 us; speedup vs baseline: 1.9263x; 1.0541x over previous
//
#include <hip/hip_runtime.h>
#include <hip/hip_fp16.h>
#include <math.h>

#define NTHREADS 256
#define G3   4096
#define DW3  3375
#define VOL  64
#define VOL3 (VOL*VOL*VOL)
#define NSL  10          // z-slices per chunk
#define POOLF 6859       // shared pool floats (filter peak 19^3); staging 3240*2=6480 fits
#define GSP  17

#if defined(__has_builtin)
#if __has_builtin(__builtin_amdgcn_fdot2)
#define HAS_FDOT2 1
#endif
#endif

typedef unsigned int uint;
typedef _Float16 h2v __attribute__((ext_vector_type(2)));

__device__ __forceinline__ float dot2acc(__half2 a, float c) {
#ifdef HAS_FDOT2
    h2v av = __builtin_bit_cast(h2v, a);
    return __builtin_amdgcn_fdot2(av, av, c, false);
#else
    float2 af = __half22float2(a);
    return fmaf(af.x, af.x, fmaf(af.y, af.y, c));
#endif
}

// typed load/store helpers (fp32 math everywhere; fp16 only as storage)
__device__ __forceinline__ float ldv(const float* p)  { return *p; }
__device__ __forceinline__ float ldv(const __half* p) { return __half2float(*p); }
__device__ __forceinline__ void  stv(float* p, float v)  { *p = v; }
__device__ __forceinline__ void  stv(__half* p, float v) { *p = __float2half(v); }

// ---------------------------------------------------------------------------
// Prepack feat50 into 2 channel-packed fp16x4 volumes: P[p][z][y][x] = uint2
// ---------------------------------------------------------------------------
__global__ __launch_bounds__(NTHREADS) void k_prepack(
    const float* __restrict__ f, uint2* __restrict__ P)
{
    int v = blockIdx.x * NTHREADS + threadIdx.x;      // grid = VOL3/256 exact
    float c0 = f[v],        c1 = f[VOL3 + v],   c2 = f[2*VOL3 + v], c3 = f[3*VOL3 + v];
    float c4 = f[4*VOL3+v], c5 = f[5*VOL3 + v], c6 = f[6*VOL3 + v], c7 = f[7*VOL3 + v];
    uint2 a, b;
    a.x = __builtin_bit_cast(uint, __floats2half2_rn(c0, c1));
    a.y = __builtin_bit_cast(uint, __floats2half2_rn(c2, c3));
    b.x = __builtin_bit_cast(uint, __floats2half2_rn(c4, c5));
    b.y = __builtin_bit_cast(uint, __floats2half2_rn(c6, c7));
    P[v] = a;
    P[VOL3 + v] = b;
}

// ---------------------------------------------------------------------------
// Displacement-domain filter, register-line version (27.4 KB LDS):
// out = avgp3(avgp3(-maxp3(-rpad3(v)))) = separable clamped min-3 (15->19)
// then separable 5-tap [1,2,3,2,1]/9 (19->15). In-place ping-pong in pool.
// ---------------------------------------------------------------------------
template<typename OUT>
__device__ __forceinline__ void disp_filter_reg(float* pool, int tid, OUT* gout)
{
    const float w0 = 1.0f/9.0f, w1 = 2.0f/9.0f, w2 = 3.0f/9.0f;
    // s1: min over x. 225 lines (z,y). in [225][15] -> out [225][19]
    {
        float r[15];
        if (tid < 225) {
            #pragma unroll
            for (int i = 0; i < 15; ++i) r[i] = pool[tid*15 + i];
        }
        __syncthreads();
        if (tid < 225) {
            #pragma unroll
            for (int x = 0; x < 19; ++x) {
                const int i0 = (x-3) < 0 ? 0 : ((x-3) > 14 ? 14 : (x-3));
                const int i1 = (x-2) < 0 ? 0 : ((x-2) > 14 ? 14 : (x-2));
                const int i2 = (x-1) < 0 ? 0 : ((x-1) > 14 ? 14 : (x-1));
                pool[tid*19 + x] = fminf(fminf(r[i0], r[i1]), r[i2]);
            }
        }
        __syncthreads();
    }
    // s2: min over y. 285 lines (z,x). in [z*15+y][19]+x -> out [15z][19y][19x]
    {
        float a[15], b[15];
        int L1 = tid + 256;
        int z0 = tid/19, x0 = tid - z0*19;
        int z1 = L1/19,  x1 = L1 - z1*19;
        bool v0 = tid < 285, v1 = L1 < 285;
        if (v0) {
            #pragma unroll
            for (int y = 0; y < 15; ++y) a[y] = pool[(z0*15 + y)*19 + x0];
        }
        if (v1) {
            #pragma unroll
            for (int y = 0; y < 15; ++y) b[y] = pool[(z1*15 + y)*19 + x1];
        }
        __syncthreads();
        #pragma unroll
        for (int y = 0; y < 19; ++y) {
            const int i0 = (y-3) < 0 ? 0 : ((y-3) > 14 ? 14 : (y-3));
            const int i1 = (y-2) < 0 ? 0 : ((y-2) > 14 ? 14 : (y-2));
            const int i2 = (y-1) < 0 ? 0 : ((y-1) > 14 ? 14 : (y-1));
            if (v0) pool[z0*361 + y*19 + x0] = fminf(fminf(a[i0], a[i1]), a[i2]);
            if (v1) pool[z1*361 + y*19 + x1] = fminf(fminf(b[i0], b[i1]), b[i2]);
        }
        __syncthreads();
    }
    // s3: min over z. 361 lines (yx). in [15][361] -> out [19][361]
    {
        float a[15], b[15];
        int L1 = tid + 256;
        bool v1 = L1 < 361;
        {
            #pragma unroll
            for (int z = 0; z < 15; ++z) a[z] = pool[z*361 + tid];
        }
        if (v1) {
            #pragma unroll
            for (int z = 0; z < 15; ++z) b[z] = pool[z*361 + L1];
        }
        __syncthreads();
        #pragma unroll
        for (int z = 0; z < 19; ++z) {
            const int i0 = (z-3) < 0 ? 0 : ((z-3) > 14 ? 14 : (z-3));
            const int i1 = (z-2) < 0 ? 0 : ((z-2) > 14 ? 14 : (z-2));
            const int i2 = (z-1) < 0 ? 0 : ((z-1) > 14 ? 14 : (z-1));
            pool[z*361 + tid] = fminf(fminf(a[i0], a[i1]), a[i2]);
            if (v1) pool[z*361 + L1] = fminf(fminf(b[i0], b[i1]), b[i2]);
        }
        __syncthreads();
    }
    // s4: smooth over x. 361 lines (zy). in [361][19] -> out [361][15]
    {
        float a[19], b[19];
        int L1 = tid + 256;
        bool v1 = L1 < 361;
        #pragma unroll
        for (int x = 0; x < 19; ++x) a[x] = pool[tid*19 + x];
        if (v1) {
            #pragma unroll
            for (int x = 0; x < 19; ++x) b[x] = pool[L1*19 + x];
        }
        __syncthreads();
        #pragma unroll
        for (int i = 0; i < 15; ++i) {
            pool[tid*15 + i] = w0*(a[i]+a[i+4]) + w1*(a[i+1]+a[i+3]) + w2*a[i+2];
            if (v1) pool[L1*15 + i] = w0*(b[i]+b[i+4]) + w1*(b[i+1]+b[i+3]) + w2*b[i+2];
        }
        __syncthreads();
    }
    // s5: smooth over y. 285 lines (z,x). in [z*19+y][15]+x -> out [z*15+y][15]+x
    {
        float a[19], b[19];
        int L1 = tid + 256;
        int z0 = tid/15, x0 = tid - z0*15;
        int z1 = L1/15,  x1 = L1 - z1*15;
        bool v0 = tid < 285, v1 = L1 < 285;
        if (v0) {
            #pragma unroll
            for (int y = 0; y < 19; ++y) a[y] = pool[(z0*19 + y)*15 + x0];
        }
        if (v1) {
            #pragma unroll
            for (int y = 0; y < 19; ++y) b[y] = pool[(z1*19 + y)*15 + x1];
        }
        __syncthreads();
        #pragma unroll
        for (int i = 0; i < 15; ++i) {
            if (v0) pool[(z0*15 + i)*15 + x0] = w0*(a[i]+a[i+4]) + w1*(a[i+1]+a[i+3]) + w2*a[i+2];
            if (v1) pool[(z1*15 + i)*15 + x1] = w0*(b[i]+b[i+4]) + w1*(b[i+1]+b[i+3]) + w2*b[i+2];
        }
        __syncthreads();
    }
    // s6: smooth over z. 225 lines (yx). in [19][225] -> out [15][225], then copy out.
    {
        float a[19];
        if (tid < 225) {
            #pragma unroll
            for (int z = 0; z < 19; ++z) a[z] = pool[z*225 + tid];
        }
        __syncthreads();
        if (tid < 225) {
            #pragma unroll
            for (int i = 0; i < 15; ++i)
                pool[i*225 + tid] = w0*(a[i]+a[i+4]) + w1*(a[i+1]+a[i+3]) + w2*a[i+2];
        }
        __syncthreads();
        for (int e = tid; e < DW3; e += NTHREADS) stv(gout + e, pool[e]);
    }
}

// ---------------------------------------------------------------------------
// K1: per grid point — packed-fp16 trilinear SSD (2 ch-groups x 2 z-chunks,
// 10x18x18 staged windows, register ssd) + fused register-line filter.
// ---------------------------------------------------------------------------
template<typename C1>
__global__ __launch_bounds__(NTHREADS,5) void k1_sample(
    const float* __restrict__ feat00, const uint2* __restrict__ P,
    const float* __restrict__ grid_xyz, const float* __restrict__ alpha,
    __half* __restrict__ deeds, C1* __restrict__ cost1)
{
    __shared__ __align__(16) float pool[POOLF];
    __shared__ int4 tabx[15], taby[15], tabz[15];
    __shared__ float fixedv[8];
    __shared__ int   loS[2];     // x, y window base
    __shared__ int   lozS[2];    // z base per chunk
    __shared__ float gpos[3];

    const int tid = threadIdx.x;
    const int g = blockIdx.x;

    if (tid < 3) gpos[tid] = (grid_xyz[g*3 + tid] + 1.0f) * 31.5f;   // [0,63]
    __syncthreads();
    if (tid < 2) {
        int lo = (int)floorf(gpos[tid]) - 8;
        loS[tid] = lo < 0 ? 0 : (lo > 46 ? 46 : lo);
    } else if (tid < 4) {
        int k = (tid - 2) * 8;                    // k=0 -> chunk0, k=8 -> chunk1
        float pz = gpos[2] + (1.125f*(float)k - 7.875f);
        pz = fminf(fmaxf(pz, 0.0f), 63.0f);
        lozS[tid-2] = (int)floorf(pz);
    }
    __syncthreads();
    if (tid < 45) {   // per-axis tables {frac_bits, byteoff(i0), byteoff(i1)}
        int ax = tid / 15, k = tid - ax*15;
        float p = gpos[ax] + (1.125f*(float)k - 7.875f);
        p = fminf(fmaxf(p, 0.0f), 63.0f);
        float f = floorf(p);
        int i0 = (int)f;
        int i1 = i0 + 1 > 63 ? 63 : i0 + 1;
        int lo = (ax == 2) ? lozS[k < 8 ? 0 : 1] : loS[ax];
        int sc = (ax == 0) ? 8 : (ax == 1) ? 144 : 2592;   // byte strides (8B/voxel)
        int4 e;
        e.x = __float_as_int(p - f);
        e.y = (i0 - lo) * sc;
        e.z = (i1 - lo) * sc;
        e.w = 0;
        ((ax == 0) ? tabx : (ax == 1) ? taby : tabz)[k] = e;
    }
    if (tid < 8) {    // fixed sample from feat00 (fp32 exact)
        float px = gpos[0], py = gpos[1], pz = gpos[2];
        int x0 = (int)floorf(px), y0 = (int)floorf(py), z0 = (int)floorf(pz);
        float tx = px-(float)x0, ty = py-(float)y0, tz = pz-(float)z0;
        int x1 = x0+1>63?63:x0+1, y1 = y0+1>63?63:y0+1, z1 = z0+1>63?63:z0+1;
        const float* F = feat00 + (size_t)tid * VOL3;
        float v000=F[(z0*64+y0)*64+x0], v001=F[(z0*64+y0)*64+x1];
        float v010=F[(z0*64+y1)*64+x0], v011=F[(z0*64+y1)*64+x1];
        float v100=F[(z1*64+y0)*64+x0], v101=F[(z1*64+y0)*64+x1];
        float v110=F[(z1*64+y1)*64+x0], v111=F[(z1*64+y1)*64+x1];
        float wx0=1.0f-tx, wy0=1.0f-ty, wz0=1.0f-tz;
        fixedv[tid] =
            wz0*(wy0*(wx0*v000 + tx*v001) + ty*(wx0*v010 + tx*v011)) +
            tz *(wy0*(wx0*v100 + tx*v101) + ty*(wx0*v110 + tx*v111));
    }
    // RACE FIX (R8): fixedv read by ALL threads at the p-loop top below.
    __syncthreads();

    float s0[8], s1[7];
    #pragma unroll
    for (int j = 0; j < 8; ++j) s0[j] = 0.0f;
    #pragma unroll
    for (int j = 0; j < 7; ++j) s1[j] = 0.0f;

    const __half2 hz = __floats2half2_rn(0.0f, 0.0f);

    #define CORNER(ADDR, W) { \
        uint2 cc = *(const uint2*)(base + (ADDR)); \
        __half2 wh = __floats2half2_rn((W), (W)); \
        m01 = __hfma2(__builtin_bit_cast(__half2, cc.x), wh, m01); \
        m23 = __hfma2(__builtin_bit_cast(__half2, cc.y), wh, m23); }

    #define SAMPLE(DD, ACC) { \
        int kx = (DD) % 15; int t2 = (DD) / 15; int ky = t2 % 15; int kz = t2 / 15; \
        int4 X = tabx[kx]; int4 Y = taby[ky]; int4 Z = tabz[kz]; \
        float tx = __int_as_float(X.x), ty = __int_as_float(Y.x), tz = __int_as_float(Z.x); \
        float sx = 1.0f-tx, sy = 1.0f-ty, sz = 1.0f-tz; \
        float Aw = sz*sy, Bw = sz*ty, Cw = tz*sy, Dw = tz*ty; \
        int a00 = Z.y+Y.y, a01 = Z.y+Y.z, a10 = Z.z+Y.y, a11 = Z.z+Y.z; \
        __half2 m01 = hz, m23 = hz; \
        CORNER(a00+X.y, Aw*sx) CORNER(a00+X.z, Aw*tx) \
        CORNER(a01+X.y, Bw*sx) CORNER(a01+X.z, Bw*tx) \
        CORNER(a10+X.y, Cw*sx) CORNER(a10+X.z, Cw*tx) \
        CORNER(a11+X.y, Dw*sx) CORNER(a11+X.z, Dw*tx) \
        __half2 d01 = __hsub2(f01, m01), d23 = __hsub2(f23, m23); \
        ACC = dot2acc(d01, dot2acc(d23, ACC)); }

    for (int p = 0; p < 2; ++p) {
        const uint2* Pv = P + (size_t)p * VOL3;
        const int lx = loS[0], ly = loS[1];
        __half2 f01 = __floats2half2_rn(fixedv[4*p+0], fixedv[4*p+1]);
        __half2 f23 = __floats2half2_rn(fixedv[4*p+2], fixedv[4*p+3]);
        for (int c = 0; c < 2; ++c) {
            __syncthreads();                      // prior pool reads done
            const int lz = lozS[c];
            for (int e = tid; e < NSL*18*18; e += NTHREADS) {    // 3240 voxels
                int rz = e / 324; int rem = e - rz*324; int ry = rem / 18; int rx = rem - ry*18;
                int zz = lz + rz; zz = zz > 63 ? 63 : zz;
                ((uint2*)pool)[e] = Pv[(zz*64 + (ly+ry))*64 + (lx+rx)];
            }
            __syncthreads();
            const char* base = (const char*)pool;
            if (c == 0) {
                #pragma unroll
                for (int j = 0; j < 8; ++j) {
                    int d = tid + j*NTHREADS;
                    if (d < 1800) SAMPLE(d, s0[j])
                }
            } else {
                #pragma unroll
                for (int j = 0; j < 7; ++j) {
                    int d = 1800 + tid + j*NTHREADS;
                    if (d < DW3) SAMPLE(d, s1[j])
                }
            }
        }
    }
    #undef SAMPLE
    #undef CORNER

    const float a0 = alpha[0], a1 = alpha[1];
    __syncthreads();                              // staging reads complete
    __half* gd = deeds + (size_t)g * DW3;
    #pragma unroll
    for (int j = 0; j < 8; ++j) {
        int d = tid + j*NTHREADS;
        if (d < 1800) { float cv = fmaf(a0, s0[j], a1); gd[d] = __float2half(cv); pool[d] = cv; }
    }
    #pragma unroll
    for (int j = 0; j < 7; ++j) {
        int d = 1800 + tid + j*NTHREADS;
        if (d < DW3) { float cv = fmaf(a0, s1[j], a1); gd[d] = __float2half(cv); pool[d] = cv; }
    }
    __syncthreads();
    disp_filter_reg(pool, tid, cost1 + (size_t)g * DW3);
}

// ---------------------------------------------------------------------------
// K3: cost2 = a4 + a2*deeds + a3*avg1, then displacement filter. Output fp32.
// ---------------------------------------------------------------------------
template<typename A1>
__global__ __launch_bounds__(NTHREADS,5) void k3_second(
    const __half* __restrict__ deeds, const A1* avg1,
    const float* __restrict__ alpha, float* costb)
{
    __shared__ __align__(16) float pool[POOLF];
    const int tid = threadIdx.x;
    const int g = blockIdx.x;
    const float a2 = alpha[2], a3 = alpha[3], a4 = alpha[4];
    const __half* dg = deeds + (size_t)g*DW3;
    const A1* ag = avg1 + (size_t)g*DW3;
    for (int d = tid; d < DW3; d += NTHREADS)
        pool[d] = a4 + a2*__half2float(dg[d]) + a3*ldv(ag + d);
    __syncthreads();
    disp_filter_reg(pool, tid, costb + (size_t)g*DW3);
}

// ---------------------------------------------------------------------------
// Grid-domain smoothing (separable clamped 5-tap [1,2,3,2,1]/9 over 16^3),
// two coalesced kernels over 16-d line tiles; fp32 math, T storage.
// ---------------------------------------------------------------------------
__device__ __forceinline__ void smooth16(const float* r, float* o)
{
    const float w0 = 1.0f/9.0f, w1 = 2.0f/9.0f, w2 = 3.0f/9.0f;
    #pragma unroll
    for (int i = 0; i < 16; ++i) {
        const int m2 = i<2?0:i-2, m1 = i<1?0:i-1, p1 = i>14?15:i+1, p2 = i>13?15:i+2;
        o[i] = w0*(r[m2]+r[p2]) + w1*(r[m1]+r[p1]) + w2*r[i];
    }
}

template<typename T>
__global__ __launch_bounds__(NTHREADS) void k_smooth_xy(T* buf)
{
    __shared__ float t[16*16*GSP];
    const int tid = threadIdx.x;
    const int d0 = blockIdx.x * 16;
    const int gz = blockIdx.y;
    const int dd = tid & 15, sub = tid >> 4;
    const int d = d0 + dd;
    const bool dok = d < DW3;
    for (int it = 0; it < 16; ++it) {
        int gyx = it*16 + sub;
        t[gyx*GSP + dd] = dok ? ldv(buf + (size_t)(gz*256 + gyx)*DW3 + d) : 0.0f;
    }
    __syncthreads();
    {   // x-pass: thread (gy=sub, dd)
        float r[16], o[16];
        int b = sub*(16*GSP) + dd;
        #pragma unroll
        for (int k = 0; k < 16; ++k) r[k] = t[b + k*GSP];
        smooth16(r, o);
        #pragma unroll
        for (int k = 0; k < 16; ++k) t[b + k*GSP] = o[k];
    }
    __syncthreads();
    {   // y-pass: thread (gx=sub, dd)
        float r[16], o[16];
        int b = sub*GSP + dd;
        #pragma unroll
        for (int k = 0; k < 16; ++k) r[k] = t[b + k*(16*GSP)];
        smooth16(r, o);
        #pragma unroll
        for (int k = 0; k < 16; ++k) t[b + k*(16*GSP)] = o[k];
    }
    __syncthreads();
    for (int it = 0; it < 16; ++it) {
        int gyx = it*16 + sub;
        if (dok) stv(buf + (size_t)(gz*256 + gyx)*DW3 + d, t[gyx*GSP + dd]);
    }
}

// z pass; reads T in, writes U out (allows fp16 chain -> fp32 avg2 handoff).
template<typename T, typename U>
__global__ __launch_bounds__(NTHREADS) void k_smooth_z(const T* in, U* out)
{
    __shared__ float t[32*16*GSP];
    const int tid = threadIdx.x;
    const int d0 = blockIdx.x * 16;
    const int gyx0 = blockIdx.y * 32;
    const int dd = tid & 15, sub = tid >> 4;
    const int d = d0 + dd;
    const bool dok = d < DW3;
    for (int it = 0; it < 32; ++it) {
        int p = it*16 + sub;
        int gyxl = p >> 4, gz = p & 15;
        t[(gyxl*16 + gz)*GSP + dd] = dok ? ldv(in + (size_t)(gz*256 + gyx0 + gyxl)*DW3 + d) : 0.0f;
    }
    __syncthreads();
    for (int c = tid; c < 512; c += NTHREADS) {
        int gyxl = c >> 4, ddl = c & 15;
        float r[16], o[16];
        int b = gyxl*(16*GSP) + ddl;
        #pragma unroll
        for (int k = 0; k < 16; ++k) r[k] = t[b + k*GSP];
        smooth16(r, o);
        #pragma unroll
        for (int k = 0; k < 16; ++k) t[b + k*GSP] = o[k];
    }
    __syncthreads();
    for (int it = 0; it < 32; ++it) {
        int p = it*16 + sub;
        int gyxl = p >> 4, gz = p & 15;
        if (dok) stv(out + (size_t)(gz*256 + gyx0 + gyxl)*DW3 + d, t[(gyxl*16 + gz)*GSP + dd]);
    }
}

// ---------------------------------------------------------------------------
// K5: row softmax over 3375 (logits = -a5*cost) + displacement expectation.
// ---------------------------------------------------------------------------
#define J14 14
__global__ __launch_bounds__(NTHREADS) void k5_softmax(
    const float* avg2, const float* __restrict__ shift,
    const float* __restrict__ alpha, float* __restrict__ out_soft,
    float* __restrict__ out_pred)
{
    __shared__ float wmax[4];
    __shared__ float wred[4][4];
    const int tid = threadIdx.x;
    const int g = blockIdx.x;
    const int lane = tid & 63, wid = tid >> 6;
    const float a5 = alpha[5];
    const float* src = avg2 + (size_t)g*DW3;

    float L[J14];
    float mx = -INFINITY;
    #pragma unroll
    for (int j = 0; j < J14; ++j) {
        int d = tid + j*NTHREADS;
        float val = (d < DW3) ? (-a5 * src[d]) : -INFINITY;
        L[j] = val;
        mx = fmaxf(mx, val);
    }
    #pragma unroll
    for (int off = 32; off > 0; off >>= 1)
        mx = fmaxf(mx, __shfl_down(mx, off));
    if (lane == 0) wmax[wid] = mx;
    __syncthreads();
    mx = fmaxf(fmaxf(wmax[0], wmax[1]), fmaxf(wmax[2], wmax[3]));

    float E[J14];
    float s = 0.0f, px = 0.0f, py = 0.0f, pz = 0.0f;
    #pragma unroll
    for (int j = 0; j < J14; ++j) {
        int d = tid + j*NTHREADS;
        E[j] = 0.0f;
        if (d < DW3) {
            float e = __expf(L[j] - mx);
            E[j] = e;
            s += e;
            px = fmaf(e, shift[d*3+0], px);
            py = fmaf(e, shift[d*3+1], py);
            pz = fmaf(e, shift[d*3+2], pz);
        }
    }
    #pragma unroll
    for (int off = 32; off > 0; off >>= 1) {
        s  += __shfl_down(s, off);
        px += __shfl_down(px, off);
        py += __shfl_down(py, off);
        pz += __shfl_down(pz, off);
    }
    if (lane == 0) { wred[wid][0]=s; wred[wid][1]=px; wred[wid][2]=py; wred[wid][3]=pz; }
    __syncthreads();
    float st = wred[0][0]+wred[1][0]+wred[2][0]+wred[3][0];
    float inv = 1.0f / st;
    float* dst = out_soft + (size_t)g*DW3;
    #pragma unroll
    for (int j = 0; j < J14; ++j) {
        int d = tid + j*NTHREADS;
        if (d < DW3) dst[d] = E[j]*inv;
    }
    if (tid == 0) {
        out_pred[g*3+0] = (wred[0][1]+wred[1][1]+wred[2][1]+wred[3][1])*inv;
        out_pred[g*3+1] = (wred[0][2]+wred[1][2]+wred[2][2]+wred[3][2])*inv;
        out_pred[g*3+2] = (wred[0][3]+wred[1][3]+wred[2][3]+wred[3][3])*inv;
    }
}

// ---------------------------------------------------------------------------
// Memory plan A (ws >= 59.5 MB):
//   d_ws : deeds fp16 (27.65MB) | P (4MB) | cost1/avg1 fp16 (27.65MB)
//   d_out: cost2/avg2 fp32 (k3 out -> smooth#2 -> k5 in-place) | pred
// Fallback B (R9 layout): cost1 fp32 in d_out, chain1 fp32.
// ---------------------------------------------------------------------------
extern "C" void kernel_launch(void* const* d_in, const int* in_sizes, int n_in,
                              void* d_out, int out_size, void* d_ws, size_t ws_size,
                              hipStream_t stream)
{
    const float* feat00 = (const float*)d_in[0];
    const float* feat50 = (const float*)d_in[1];
    const float* grid   = (const float*)d_in[2];
    const float* shift  = (const float*)d_in[5];
    const float* alpha  = (const float*)d_in[6];

    const size_t halfbytes = (size_t)G3*DW3*sizeof(__half);        // 27,648,000
    __half* deeds = (__half*)d_ws;
    uint2*  P     = (uint2*)((char*)d_ws + halfbytes);
    float*  cbuf  = (float*)d_out;                                  // chain-2 fp32
    float*  pred  = (float*)d_out + (size_t)G3*DW3;
    const size_t needA = halfbytes + (size_t)2*VOL3*sizeof(uint2) + halfbytes;

    dim3 gxy(211, 16), gz(211, 8);
    k_prepack<<<VOL3/NTHREADS, NTHREADS, 0, stream>>>(feat50, P);

    if (ws_size >= needA) {
        __half* c1 = (__half*)((char*)d_ws + halfbytes + (size_t)2*VOL3*sizeof(uint2));
        k1_sample<__half><<<G3, NTHREADS, 0, stream>>>(feat00, P, grid, alpha, deeds, c1);
        k_smooth_xy<__half><<<gxy, NTHREADS, 0, stream>>>(c1);
        k_smooth_z<__half,__half><<<gz, NTHREADS, 0, stream>>>(c1, c1);
        k3_second<__half><<<G3, NTHREADS, 0, stream>>>(deeds, c1, alpha, cbuf);
    } else {
        float* c1 = cbuf;                                           // R9 fallback
        k1_sample<float><<<G3, NTHREADS, 0, stream>>>(feat00, P, grid, alpha, deeds, c1);
        k_smooth_xy<float><<<gxy, NTHREADS, 0, stream>>>(c1);
        k_smooth_z<float,float><<<gz, NTHREADS, 0, stream>>>(c1, c1);
        k3_second<float><<<G3, NTHREADS, 0, stream>>>(deeds, c1, alpha, cbuf);
    }
    k_smooth_xy<float><<<gxy, NTHREADS, 0, stream>>>(cbuf);
    k_smooth_z<float,float><<<gz, NTHREADS, 0, stream>>>(cbuf, cbuf);
    k5_softmax<<<G3, NTHREADS, 0, stream>>>(cbuf, shift, alpha, cbuf, pred);
}